// Round 17
// baseline (1759.530 us; speedup 1.0000x reference)
//
#include <hip/hip_runtime.h>

// MeshGNN f16-MFMA v16. N=50000, E=600000, H=128, L=4.
// R17 fix: R16's edge_kernel_v11 had a leftover staging block writing
// dss[129..384] in a 258-entry array -> LDS OOB corruption (absmax 1336).
// dss[1+t] with t=0..255 already covers all entries; stray block deleted.
// Design unchanged: 2-tile pipelined edge kernel (weights staged once per
// 256 edges; tile-B gather issued after tile-A frags built, hiding B's
// gather latency under A's MFMA+reduce). Tripwire: FETCH>150MB = spill.

typedef _Float16 f16x8 __attribute__((ext_vector_type(8)));
typedef _Float16 f16x2 __attribute__((ext_vector_type(2)));
typedef __fp16  fp16x2 __attribute__((ext_vector_type(2)));
typedef float f32x4 __attribute__((ext_vector_type(4)));

__device__ inline uint pk2(float a, float b) {
  fp16x2 h = __builtin_amdgcn_cvt_pkrtz(a, b);
  return __builtin_bit_cast(uint, h);
}
__device__ inline ushort f2h(float f) {
  fp16x2 h = __builtin_amdgcn_cvt_pkrtz(f, 0.f);
  return (ushort)__builtin_bit_cast(uint, h);
}
__device__ inline f16x2 bch(uint u) { return __builtin_bit_cast(f16x2, u); }

template <int NT>
__device__ inline void stage_w(ushort* Ws, const ushort* __restrict__ Wt, int t) {
#pragma unroll
  for (int i = t; i < 2048; i += NT) {
    int r = i >> 4, c = i & 15;
    *(uint4*)&Ws[r * 136 + c * 8] = *(const uint4*)&Wt[r * 128 + c * 8];
  }
}
__device__ inline void mfma_4ks(f32x4* acc, const ushort* A, const ushort* Ws,
                                int wave, int lane) {
  int cl = lane & 15, kq = (lane >> 4) * 8;
  int arow = (wave * 16 + cl) * 136;
#pragma unroll
  for (int ks = 0; ks < 4; ++ks) {
    f16x8 af = *(const f16x8*)&A[arow + ks * 32 + kq];
#pragma unroll
    for (int ct = 0; ct < 8; ++ct) {
      f16x8 bf = *(const f16x8*)&Ws[(ct * 16 + cl) * 136 + ks * 32 + kq];
      acc[ct] = __builtin_amdgcn_mfma_f32_16x16x32_f16(af, bf, acc[ct], 0, 0, 0);
    }
  }
}
__device__ inline void mfma_regA(f32x4* acc, const f16x8* af, const ushort* Ws,
                                 int lane) {
  int cl = lane & 15, kq = (lane >> 4) * 8;
#pragma unroll
  for (int ks = 0; ks < 4; ++ks) {
#pragma unroll
    for (int ct = 0; ct < 8; ++ct) {
      f16x8 bf = *(const f16x8*)&Ws[(ct * 16 + cl) * 136 + ks * 32 + kq];
      acc[ct] = __builtin_amdgcn_mfma_f32_16x16x32_f16(af[ks], bf, acc[ct], 0, 0, 0);
    }
  }
}

// ---------------------------------------------------------------------------
__global__ __launch_bounds__(256) void count_int_kernel(const int* __restrict__ dst,
                                                        int* __restrict__ cnti, int E) {
  int e = blockIdx.x * 256 + threadIdx.x;
  if (e < E) atomicAdd(&cnti[dst[e]], 1);
}
__global__ __launch_bounds__(256) void scan_block_sum(const int* __restrict__ cnti,
                                                      int* __restrict__ bsum, int N) {
  int i = blockIdx.x * 256 + threadIdx.x;
  int v = (i < N) ? cnti[i] : 0;
#pragma unroll
  for (int o = 1; o < 64; o <<= 1) v += __shfl_xor(v, o);
  __shared__ int wsum[4];
  if ((threadIdx.x & 63) == 0) wsum[threadIdx.x >> 6] = v;
  __syncthreads();
  if (threadIdx.x == 0) bsum[blockIdx.x] = wsum[0] + wsum[1] + wsum[2] + wsum[3];
}
__global__ __launch_bounds__(256) void scan_partials(int* __restrict__ bsum, int nb) {
  __shared__ int s[256];
  int t = threadIdx.x;
  int v = (t < nb) ? bsum[t] : 0;
  s[t] = v;
  __syncthreads();
  for (int o = 1; o < 256; o <<= 1) {
    int u = (t >= o) ? s[t - o] : 0;
    __syncthreads();
    s[t] += u;
    __syncthreads();
  }
  if (t < nb) bsum[t] = s[t] - v;
}
__global__ __launch_bounds__(256) void scan_final(const int* __restrict__ cnti,
                                                  const int* __restrict__ bsum,
                                                  int* __restrict__ rowptr,
                                                  float* __restrict__ invf, int N) {
  __shared__ int s[256];
  int i = blockIdx.x * 256 + threadIdx.x;
  int t = threadIdx.x;
  int v = (i < N) ? cnti[i] : 0;
  s[t] = v;
  __syncthreads();
  for (int o = 1; o < 256; o <<= 1) {
    int u = (t >= o) ? s[t - o] : 0;
    __syncthreads();
    s[t] += u;
    __syncthreads();
  }
  if (i < N) {
    rowptr[i] = bsum[blockIdx.x] + s[t] - v;
    invf[i] = 1.f / (float)max(v, 1);
  }
}
__global__ __launch_bounds__(256) void scatter_kernel(
    const int* __restrict__ src, const int* __restrict__ dst,
    const float4* __restrict__ ea, const int* __restrict__ rowptr,
    int* __restrict__ tmpc, int* __restrict__ srcs, int* __restrict__ dsts,
    float4* __restrict__ eas, int E) {
  int e = blockIdx.x * 256 + threadIdx.x;
  if (e >= E) return;
  int d = dst[e];
  int r = atomicAdd(&tmpc[d], 1);
  int p = rowptr[d] + r;
  srcs[p] = src[e];
  dsts[p] = d;
  eas[p] = ea[e];
}

// ---------------------------------------------------------------------------
struct WPtrs { const float* src[22]; };
__global__ __launch_bounds__(256) void wconv_kernel(WPtrs p, ushort* __restrict__ wtb,
                                                    ushort* __restrict__ wlin) {
  int m = blockIdx.y;
  int idx = blockIdx.x * 256 + threadIdx.x;
  if (m == 21) {
    if (idx >= 4096) return;
    int n = idx >> 5, k = idx & 31;
    wlin[idx] = (k < 16) ? f2h(p.src[21][k * 128 + n]) : (ushort)0;
  } else {
    int n = idx >> 7, k = idx & 127;
    wtb[(size_t)m * 16384 + idx] = f2h(p.src[m][k * 128 + n]);
  }
}

// ---------------------------------------------------------------------------
__global__ __launch_bounds__(256) void lin_hw_kernel(
    const float* __restrict__ x, const ushort* __restrict__ wlin,
    const float* __restrict__ lb, const ushort* __restrict__ mw1t,
    const float* __restrict__ mb1, float* __restrict__ h,
    ushort* __restrict__ hwb, int N) {
  __shared__ char smem[69632] __attribute__((aligned(16)));
  ushort* xb  = (ushort*)smem;
  ushort* wsl = (ushort*)(smem + 4096);
  ushort* As1 = (ushort*)(smem + 12288);
  ushort* Ws  = (ushort*)(smem + 34816);
  int t = threadIdx.x, lane = t & 63, wave = t >> 6;
  int m0 = blockIdx.x * 64;
  int cl = lane & 15, kq = (lane >> 4) * 8;

  for (int i = t; i < 2048; i += 256) {
    int row = i >> 5, c = i & 31;
    int m = m0 + row;
    xb[i] = (c < 16 && m < N) ? f2h(x[(size_t)m * 16 + c]) : (ushort)0;
  }
  for (int i = t; i < 4096 / 8; i += 256)
    *(uint4*)&wsl[i * 8] = *(const uint4*)&wlin[i * 8];
  stage_w<256>(Ws, mw1t, t);
  __syncthreads();

  f32x4 acc[8];
#pragma unroll
  for (int i = 0; i < 8; ++i)
#pragma unroll
    for (int j = 0; j < 4; ++j) acc[i][j] = 0.f;
  {
    f16x8 af = *(const f16x8*)&xb[(wave * 16 + cl) * 32 + kq];
#pragma unroll
    for (int ct = 0; ct < 8; ++ct) {
      f16x8 bf = *(const f16x8*)&wsl[(ct * 16 + cl) * 32 + kq];
      acc[ct] = __builtin_amdgcn_mfma_f32_16x16x32_f16(af, bf, acc[ct], 0, 0, 0);
    }
  }
#pragma unroll
  for (int reg = 0; reg < 4; ++reg) {
    int row = wave * 16 + (lane >> 4) * 4 + reg;
    int m = m0 + row;
#pragma unroll
    for (int ct = 0; ct < 8; ++ct) {
      int col = ct * 16 + cl;
      float v = fmaxf(acc[ct][reg] + lb[col], 0.f);
      if (m < N) h[(size_t)m * 128 + col] = v;
      As1[row * 136 + col] = f2h(v);
    }
  }
  __syncthreads();
  f32x4 acc2[8];
#pragma unroll
  for (int i = 0; i < 8; ++i)
#pragma unroll
    for (int j = 0; j < 4; ++j) acc2[i][j] = 0.f;
  mfma_4ks(acc2, As1, Ws, wave, lane);
#pragma unroll
  for (int reg = 0; reg < 4; ++reg) {
    int m = m0 + wave * 16 + (lane >> 4) * 4 + reg;
    if (m >= N) continue;
#pragma unroll
    for (int ct = 0; ct < 8; ++ct) {
      int col = ct * 16 + cl;
      hwb[(size_t)m * 128 + col] = f2h(acc2[ct][reg] + mb1[col]);
    }
  }
}

// ---------------------------------------------------------------------------
// helpers for the 2-tile edge kernel
__device__ inline void build_m1(f16x8* af0, f16x8* af1, const uint4* hv0,
                                const uint4* hv1, const uint (*weaH)[4],
                                const uint* e0b, const uint* e1b, int g) {
  f16x2 z2 = {};
#pragma unroll
  for (int ks = 0; ks < 4; ++ks) {
    union { uint u32[4]; f16x8 v; } o0, o1;
    const uint* q0 = (const uint*)&hv0[ks];
    const uint* q1 = (const uint*)&hv1[ks];
    int k2b = ks * 16 + g * 4;
#pragma unroll
    for (int p = 0; p < 4; ++p) {
      uint4 w4 = *(const uint4*)&weaH[k2b + p][0];
      f16x2 m0h = bch(q0[p]);
      f16x2 m1h = bch(q1[p]);
      m0h += bch(e0b[0]) * bch(w4.x); m1h += bch(e1b[0]) * bch(w4.x);
      m0h += bch(e0b[1]) * bch(w4.y); m1h += bch(e1b[1]) * bch(w4.y);
      m0h += bch(e0b[2]) * bch(w4.z); m1h += bch(e1b[2]) * bch(w4.z);
      m0h += bch(e0b[3]) * bch(w4.w); m1h += bch(e1b[3]) * bch(w4.w);
      o0.u32[p] = __builtin_bit_cast(uint, __builtin_elementwise_max(m0h, z2));
      o1.u32[p] = __builtin_bit_cast(uint, __builtin_elementwise_max(m1h, z2));
    }
    af0[ks] = o0.v; af1[ks] = o1.v;
  }
}
__device__ inline void mfma_bias(f32x4* acc0, f32x4* acc1, const f16x8* af0,
                                 const f16x8* af1, const ushort* Ws,
                                 const float* b2s, int cl, int g) {
#pragma unroll
  for (int i = 0; i < 8; ++i)
#pragma unroll
    for (int j = 0; j < 4; ++j) { acc0[i][j] = 0.f; acc1[i][j] = 0.f; }
#pragma unroll
  for (int ks = 0; ks < 4; ++ks) {
#pragma unroll
    for (int ct = 0; ct < 8; ++ct) {
      f16x8 bf = *(const f16x8*)&Ws[(ct * 16 + cl) * 136 + ks * 32 + g * 8];
      acc0[ct] = __builtin_amdgcn_mfma_f32_16x16x32_f16(af0[ks], bf, acc0[ct], 0, 0, 0);
      acc1[ct] = __builtin_amdgcn_mfma_f32_16x16x32_f16(af1[ks], bf, acc1[ct], 0, 0, 0);
    }
  }
#pragma unroll
  for (int ct = 0; ct < 8; ++ct) {
    float bb = b2s[ct * 16 + cl];
#pragma unroll
    for (int reg = 0; reg < 4; ++reg) {
      acc0[ct][reg] = fmaxf(acc0[ct][reg] + bb, 0.f);
      acc1[ct][reg] = fmaxf(acc1[ct][reg] + bb, 0.f);
    }
  }
}
__device__ inline void seg_reduce(const f32x4* acc0, const f32x4* acc1,
                                  int dmy, int dpv, int dafter,
                                  float* __restrict__ agg, int cl, int g) {
  unsigned long long bmv = __ballot(dmy != dpv);
  unsigned mask32 = (unsigned)bmv | 1u;
  bool firstClosed = ((unsigned)bmv & 1u) != 0;
  while (mask32) {
    int rOff = __ffs(mask32) - 1;
    unsigned rest = mask32 & (mask32 - 1);
    int eOff = rest ? (__ffs(rest) - 1) : 32;
    mask32 = rest;
    int d = __shfl(dmy, rOff);
    if (d < 0) continue;
    bool openL = (rOff == 0) && !firstClosed;
    bool openR = (eOff == 32) && (dafter == d);
    float ps[8];
#pragma unroll
    for (int ct = 0; ct < 8; ++ct) ps[ct] = 0.f;
#pragma unroll
    for (int reg = 0; reg < 4; ++reg) {
      int r0w = g * 4 + reg;
      bool in0 = (r0w >= rOff) && (r0w < eOff);
      bool in1 = (r0w + 16 >= rOff) && (r0w + 16 < eOff);
#pragma unroll
      for (int ct = 0; ct < 8; ++ct) {
        if (in0) ps[ct] += acc0[ct][reg];
        if (in1) ps[ct] += acc1[ct][reg];
      }
    }
#pragma unroll
    for (int ct = 0; ct < 8; ++ct) {
      ps[ct] += __shfl_xor(ps[ct], 16);
      ps[ct] += __shfl_xor(ps[ct], 32);
    }
    if (g == 0) {
      float* ag = &agg[(size_t)d * 128 + cl];
      if (openL || openR) {
#pragma unroll
        for (int ct = 0; ct < 8; ++ct) atomicAdd(&ag[ct * 16], ps[ct]);
      } else {
#pragma unroll
        for (int ct = 0; ct < 8; ++ct) ag[ct * 16] = ps[ct];
      }
    }
  }
}

// edge kernel v11: 256 threads, TWO 128-edge tiles per block, pipelined.
__global__ __launch_bounds__(256, 4) void edge_kernel_v11(
    const ushort* __restrict__ hw, const float4* __restrict__ eas,
    const int* __restrict__ srcs, const int* __restrict__ dsts,
    const ushort* __restrict__ W2t, const float* __restrict__ Wea,
    const float* __restrict__ b2, float* __restrict__ agg, int E) {
  __shared__ ushort Ws[128 * 136];
  __shared__ uint weaH[64][4];
  __shared__ float b2s[128];
  __shared__ int dss[258];   // [0]=prev, [1..256]=both tiles, [257]=next
  int t = threadIdx.x, lane = t & 63, wave = t >> 6;
  int cl = lane & 15, g = lane >> 4;
  int p0 = blockIdx.x * 256;
  int base = wave * 32;
  int rloc = lane & 31;

  // tile A scalar + hv loads (issued first)
  int eA0 = p0 + base + cl, eA1 = eA0 + 16;
  bool vA0 = eA0 < E, vA1 = eA1 < E;
  int sA0 = vA0 ? srcs[eA0] : 0, sA1 = vA1 ? srcs[eA1] : 0;
  float4 eaA0 = vA0 ? eas[eA0] : make_float4(0.f, 0.f, 0.f, 0.f);
  float4 eaA1 = vA1 ? eas[eA1] : make_float4(0.f, 0.f, 0.f, 0.f);
  uint4 hvA0[4], hvA1[4];
  {
    const ushort* h0 = hw + (size_t)sA0 * 128 + g * 8;
    const ushort* h1 = hw + (size_t)sA1 * 128 + g * 8;
#pragma unroll
    for (int ks = 0; ks < 4; ++ks) {
      hvA0[ks] = vA0 ? *(const uint4*)&h0[ks * 32] : make_uint4(0, 0, 0, 0);
      hvA1[ks] = vA1 ? *(const uint4*)&h1[ks * 32] : make_uint4(0, 0, 0, 0);
    }
  }
  // tile B scalar loads (hv deferred until A's hv consumed)
  int eB0 = eA0 + 128, eB1 = eA1 + 128;
  bool vB0 = eB0 < E, vB1 = eB1 < E;
  int sB0 = vB0 ? srcs[eB0] : 0, sB1 = vB1 ? srcs[eB1] : 0;
  float4 eaB0 = vB0 ? eas[eB0] : make_float4(0.f, 0.f, 0.f, 0.f);
  float4 eaB1 = vB1 ? eas[eB1] : make_float4(0.f, 0.f, 0.f, 0.f);

  // cooperative staging (dss[1+t] with t=0..255 covers ALL 256 tile entries)
  stage_w<256>(Ws, W2t, t);
  if (t < 64) {
    weaH[t][0] = pk2(Wea[2 * t], Wea[2 * t + 1]);
    weaH[t][1] = pk2(Wea[128 + 2 * t], Wea[128 + 2 * t + 1]);
    weaH[t][2] = pk2(Wea[256 + 2 * t], Wea[256 + 2 * t + 1]);
    weaH[t][3] = pk2(Wea[384 + 2 * t], Wea[384 + 2 * t + 1]);
  }
  if (t < 128) b2s[t] = b2[t];
  dss[1 + t] = (p0 + t < E) ? dsts[p0 + t] : -1;
  if (t == 0) dss[0] = (p0 > 0) ? dsts[p0 - 1] : -2;
  if (t == 1) dss[257] = (p0 + 256 < E) ? dsts[p0 + 256] : -3;
  __syncthreads();   // the only barrier

  // -------- tile A --------
  {
    uint e0b[4] = {pk2(eaA0.x, eaA0.x), pk2(eaA0.y, eaA0.y), pk2(eaA0.z, eaA0.z), pk2(eaA0.w, eaA0.w)};
    uint e1b[4] = {pk2(eaA1.x, eaA1.x), pk2(eaA1.y, eaA1.y), pk2(eaA1.z, eaA1.z), pk2(eaA1.w, eaA1.w)};
    f16x8 af0[4], af1[4];
    build_m1(af0, af1, hvA0, hvA1, weaH, e0b, e1b, g);   // consumes hvA

    // issue tile B hv gather now (overlaps A's MFMA + reduce)
    uint4 hvB0[4], hvB1[4];
    {
      const ushort* h0 = hw + (size_t)sB0 * 128 + g * 8;
      const ushort* h1 = hw + (size_t)sB1 * 128 + g * 8;
#pragma unroll
      for (int ks = 0; ks < 4; ++ks) {
        hvB0[ks] = vB0 ? *(const uint4*)&h0[ks * 32] : make_uint4(0, 0, 0, 0);
        hvB1[ks] = vB1 ? *(const uint4*)&h1[ks * 32] : make_uint4(0, 0, 0, 0);
      }
    }

    f32x4 acc0[8], acc1[8];
    mfma_bias(acc0, acc1, af0, af1, Ws, b2s, cl, g);
    seg_reduce(acc0, acc1, dss[1 + base + rloc], dss[base + rloc],
               dss[1 + base + 32], agg, cl, g);

    // -------- tile B --------
    uint f0b[4] = {pk2(eaB0.x, eaB0.x), pk2(eaB0.y, eaB0.y), pk2(eaB0.z, eaB0.z), pk2(eaB0.w, eaB0.w)};
    uint f1b[4] = {pk2(eaB1.x, eaB1.x), pk2(eaB1.y, eaB1.y), pk2(eaB1.z, eaB1.z), pk2(eaB1.w, eaB1.w)};
    build_m1(af0, af1, hvB0, hvB1, weaH, f0b, f1b, g);
    mfma_bias(acc0, acc1, af0, af1, Ws, b2s, cl, g);
    int ob = 128 + base;
    seg_reduce(acc0, acc1, dss[1 + ob + rloc], dss[ob + rloc],
               dss[1 + ob + 32], agg, cl, g);
  }
}

// ---------------------------------------------------------------------------
// fused node phase v2 (R15, kept): 512 thr / 128 rows, 5 barriers
__global__ __launch_bounds__(512, 2) void fused_update(
    const float* __restrict__ h, const float* __restrict__ agg,
    const float* __restrict__ inv, const ushort* __restrict__ Wu1a,
    const ushort* __restrict__ Wu1b, const ushort* __restrict__ Wu2,
    const float* __restrict__ b1, const float* __restrict__ b2,
    const ushort* __restrict__ Wn, const float* __restrict__ bn,
    float* __restrict__ h_out, ushort* __restrict__ hwb,
    const float* __restrict__ hw2, const float* __restrict__ hb2,
    float* __restrict__ out, int N, int is_last) {
  __shared__ char smem[69632] __attribute__((aligned(16)));
  ushort* WsA = (ushort*)smem;
  ushort* WsB = (ushort*)(smem + 34816);
  float* otile = (float*)smem;
  float* w2s   = (float*)(smem + 66560);
  int t = threadIdx.x, lane = t & 63, wave = t >> 6;
  int m0 = blockIdx.x * 128;
  int cl = lane & 15, g = lane >> 4;

  int m2r = m0 + wave * 16 + cl;
  bool mv = m2r < N;
  float sI = mv ? inv[m2r] : 0.f;
  float4 ha[8], ga[8];
  {
    size_t rb = (size_t)(mv ? m2r : 0) * 128 + g * 8;
    const float* hp = h + rb;
    const float* gp = agg + rb;
#pragma unroll
    for (int ks = 0; ks < 4; ++ks) {
      ha[ks * 2 + 0] = *(const float4*)&hp[ks * 32];
      ha[ks * 2 + 1] = *(const float4*)&hp[ks * 32 + 4];
      ga[ks * 2 + 0] = *(const float4*)&gp[ks * 32];
      ga[ks * 2 + 1] = *(const float4*)&gp[ks * 32 + 4];
    }
  }
  stage_w<512>(WsA, Wu1a, t);
  stage_w<512>(WsB, Wu1b, t);
  __syncthreads();

  f16x8 haf[4], af2[4];
#pragma unroll
  for (int ks = 0; ks < 4; ++ks) {
    union { uint u32[4]; f16x8 v; } oh, og;
    const float* fh = (const float*)&ha[ks * 2];
    const float* fg = (const float*)&ga[ks * 2];
#pragma unroll
    for (int j = 0; j < 4; ++j) {
      oh.u32[j] = pk2(fh[j * 2], fh[j * 2 + 1]);
      og.u32[j] = pk2(fg[j * 2] * sI, fg[j * 2 + 1] * sI);
    }
    haf[ks] = oh.v; af2[ks] = og.v;
  }

  f32x4 acc[8];
#pragma unroll
  for (int i = 0; i < 8; ++i)
#pragma unroll
    for (int j = 0; j < 4; ++j) acc[i][j] = 0.f;
  mfma_regA(acc, haf, WsA, lane);
  mfma_regA(acc, af2, WsB, lane);
  __syncthreads();

#pragma unroll
  for (int reg = 0; reg < 4; ++reg) {
    int row = wave * 16 + g * 4 + reg;
#pragma unroll
    for (int ct = 0; ct < 8; ++ct) {
      int col = ct * 16 + cl;
      WsB[row * 136 + col] = f2h(fmaxf(acc[ct][reg] + b1[col], 0.f));
    }
  }
  stage_w<512>(WsA, Wu2, t);
  __syncthreads();

  f32x4 acc2[8];
#pragma unroll
  for (int i = 0; i < 8; ++i)
#pragma unroll
    for (int j = 0; j < 4; ++j) acc2[i][j] = 0.f;
  mfma_4ks(acc2, WsB, WsA, wave, lane);
  __syncthreads();

#pragma unroll
  for (int reg = 0; reg < 4; ++reg) {
    int row = wave * 16 + g * 4 + reg;
    int m = m0 + row;
#pragma unroll
    for (int ct = 0; ct < 8; ++ct) {
      int col = ct * 16 + cl;
      float v = acc2[ct][reg] + b2[col];
      if (m < N) v += h[(size_t)m * 128 + col];
      v = fmaxf(v, 0.f);
      if (!is_last && m < N) h_out[(size_t)m * 128 + col] = v;
      WsB[row * 136 + col] = f2h(v);
    }
  }
  stage_w<512>(WsA, Wn, t);
  __syncthreads();

  f32x4 acc3[8];
#pragma unroll
  for (int i = 0; i < 8; ++i)
#pragma unroll
    for (int j = 0; j < 4; ++j) acc3[i][j] = 0.f;
  mfma_4ks(acc3, WsB, WsA, wave, lane);

  if (!is_last) {
#pragma unroll
    for (int reg = 0; reg < 4; ++reg) {
      int m = m0 + wave * 16 + g * 4 + reg;
      if (m >= N) continue;
#pragma unroll
      for (int ct = 0; ct < 8; ++ct) {
        int col = ct * 16 + cl;
        hwb[(size_t)m * 128 + col] = f2h(acc3[ct][reg] + bn[col]);
      }
    }
  } else {
    __syncthreads();
#pragma unroll
    for (int reg = 0; reg < 4; ++reg) {
      int row = wave * 16 + g * 4 + reg;
#pragma unroll
      for (int ct = 0; ct < 8; ++ct) {
        int col = ct * 16 + cl;
        otile[row * 130 + col] = fmaxf(acc3[ct][reg] + bn[col], 0.f);
      }
    }
    for (int i = t; i < 384; i += 512) w2s[i] = hw2[i];
    __syncthreads();
    if (t < 384) {
      int row = t / 3, c = t % 3;
      int m = m0 + row;
      if (m < N) {
        float s = hb2[c];
#pragma unroll 16
        for (int k = 0; k < 128; ++k) s += otile[row * 130 + k] * w2s[k * 3 + c];
        out[(size_t)m * 3 + c] = fmaxf(s, 0.f);
      }
    }
  }
}

// ---------------------------------------------------------------------------
extern "C" void kernel_launch(void* const* d_in, const int* in_sizes, int n_in,
                              void* d_out, int out_size, void* d_ws, size_t ws_size,
                              hipStream_t stream) {
  const float* x       = (const float*)d_in[0];
  const int*   ei      = (const int*)  d_in[1];
  const float* ea      = (const float*)d_in[2];
  const float* lin_w   = (const float*)d_in[3];
  const float* lin_b   = (const float*)d_in[4];
  const float* msg_w1  = (const float*)d_in[5];
  const float* msg_b1  = (const float*)d_in[6];
  const float* msg_w2  = (const float*)d_in[7];
  const float* msg_b2  = (const float*)d_in[8];
  const float* upd_w1  = (const float*)d_in[9];
  const float* upd_b1  = (const float*)d_in[10];
  const float* upd_w2  = (const float*)d_in[11];
  const float* upd_b2  = (const float*)d_in[12];
  const float* head_w1 = (const float*)d_in[13];
  const float* head_b1 = (const float*)d_in[14];
  const float* head_w2 = (const float*)d_in[15];
  const float* head_b2 = (const float*)d_in[16];

  int N = in_sizes[0] / 16;
  int E = in_sizes[1] / 2;
  const int* src = ei;
  const int* dst = ei + E;

  float* ws = (float*)d_ws;
  size_t NH = (size_t)N * 128;
  size_t Nr = ((size_t)N + 4) & ~(size_t)3;
  size_t Er = ((size_t)E + 3) & ~(size_t)3;
  size_t off = 0;
  float*  h    = ws + off; off += NH;
  float*  agg  = ws + off; off += NH;
  float4* eas  = (float4*)(ws + off); off += 4 * Er;
  float*  invf = ws + off; off += Nr;
  ushort* wtb  = (ushort*)(ws + off); off += (size_t)21 * 16384 / 2;
  ushort* wlin = (ushort*)(ws + off); off += 4096 / 2;
  ushort* hwb  = (ushort*)(ws + off); off += NH / 2;
  int*    cnti = (int*)(ws + off); off += Nr;
  int*    tmpc = (int*)(ws + off); off += Nr;
  int*    rowp = (int*)(ws + off); off += Nr;
  int*    srcs = (int*)(ws + off); off += Er;
  int*    dsts = (int*)(ws + off); off += Er;
  int*    bsum = (int*)(ws + off); off += 256;
  float*  out  = (float*)d_out;

  WPtrs wp;
  for (int l = 0; l < 4; ++l) {
    wp.src[l * 5 + 0] = msg_w1 + (size_t)l * 132 * 128;
    wp.src[l * 5 + 1] = msg_w2 + (size_t)l * 128 * 128;
    wp.src[l * 5 + 2] = upd_w1 + (size_t)l * 256 * 128;
    wp.src[l * 5 + 3] = upd_w1 + (size_t)l * 256 * 128 + 128 * 128;
    wp.src[l * 5 + 4] = upd_w2 + (size_t)l * 128 * 128;
  }
  wp.src[20] = head_w1;
  wp.src[21] = lin_w;

  int ngrid = (N + 63) / 64;
  int fgrid = (N + 127) / 128;
  int egrid = (E + 255) / 256;   // 2 tiles (256 edges) per block
  int nscan = (N + 255) / 256;

  hipMemsetAsync(cnti, 0, Nr * 4, stream);
  hipMemsetAsync(tmpc, 0, Nr * 4, stream);
  wconv_kernel<<<dim3(64, 22), 256, 0, stream>>>(wp, wtb, wlin);
  count_int_kernel<<<(E + 255) / 256, 256, 0, stream>>>(dst, cnti, E);
  scan_block_sum<<<nscan, 256, 0, stream>>>(cnti, bsum, N);
  scan_partials<<<1, 256, 0, stream>>>(bsum, nscan);
  scan_final<<<nscan, 256, 0, stream>>>(cnti, bsum, rowp, invf, N);
  scatter_kernel<<<(E + 255) / 256, 256, 0, stream>>>(src, dst, (const float4*)ea,
                                                      rowp, tmpc, srcs, dsts, eas, E);
  lin_hw_kernel<<<ngrid, 256, 0, stream>>>(x, wlin, lin_b, wtb, msg_b1, h, hwb, N);

  for (int l = 0; l < 4; ++l) {
    const ushort* mw2t  = wtb + (size_t)(l * 5 + 1) * 16384;
    const ushort* wu1at = wtb + (size_t)(l * 5 + 2) * 16384;
    const ushort* wu1bt = wtb + (size_t)(l * 5 + 3) * 16384;
    const ushort* wu2t  = wtb + (size_t)(l * 5 + 4) * 16384;
    const float*  wea   = msg_w1 + (size_t)l * 132 * 128 + 128 * 128;
    int last = (l == 3);
    const ushort* Wn = last ? (wtb + (size_t)20 * 16384)
                            : (wtb + (size_t)((l + 1) * 5 + 0) * 16384);
    const float* bn = last ? head_b1 : (msg_b1 + (l + 1) * 128);

    hipMemsetAsync(agg, 0, NH * sizeof(float), stream);
    edge_kernel_v11<<<egrid, 256, 0, stream>>>(hwb, eas, srcs, dsts, mw2t, wea,
                                               msg_b2 + l * 128, agg, E);
    fused_update<<<fgrid, 512, 0, stream>>>(h, agg, invf, wu1at, wu1bt, wu2t,
                                            upd_b1 + l * 128, upd_b2 + l * 128,
                                            Wn, bn, h, last ? nullptr : hwb,
                                            head_w2, head_b2, out, N, last);
  }
}

// Round 18
// 594.959 us; speedup vs baseline: 2.9574x; 2.9574x over previous
//
#include <hip/hip_runtime.h>

// MeshGNN f16-MFMA v17 == R13 best (598.4 us), restored verbatim.
// R14 (grid-stride persistent edge) and R16/17 (bounded 2-tile pipeline)
// BOTH spilled: acc(64) + prefetch(32+) + frags(16) > 128-VGPR cap of
// (256,4) -> scratch traffic 500-690MB, 4-5x regression. Conclusion: the
// single-tile in-register edge kernel is the local optimum; cross-tile
// latency hiding must come from occupancy (4 blk x 4 waves/CU), not
// intra-wave pipelining. This file re-establishes the verified optimum.

typedef _Float16 f16x8 __attribute__((ext_vector_type(8)));
typedef _Float16 f16x2 __attribute__((ext_vector_type(2)));
typedef __fp16  fp16x2 __attribute__((ext_vector_type(2)));
typedef float f32x4 __attribute__((ext_vector_type(4)));

__device__ inline uint pk2(float a, float b) {
  fp16x2 h = __builtin_amdgcn_cvt_pkrtz(a, b);
  return __builtin_bit_cast(uint, h);
}
__device__ inline ushort f2h(float f) {
  fp16x2 h = __builtin_amdgcn_cvt_pkrtz(f, 0.f);
  return (ushort)__builtin_bit_cast(uint, h);
}
__device__ inline f16x2 bch(uint u) { return __builtin_bit_cast(f16x2, u); }

template <int NT>
__device__ inline void stage_w(ushort* Ws, const ushort* __restrict__ Wt, int t) {
#pragma unroll
  for (int i = t; i < 2048; i += NT) {
    int r = i >> 4, c = i & 15;
    *(uint4*)&Ws[r * 136 + c * 8] = *(const uint4*)&Wt[r * 128 + c * 8];
  }
}
__device__ inline void mfma_4ks(f32x4* acc, const ushort* A, const ushort* Ws,
                                int wave, int lane) {
  int cl = lane & 15, kq = (lane >> 4) * 8;
  int arow = (wave * 16 + cl) * 136;
#pragma unroll
  for (int ks = 0; ks < 4; ++ks) {
    f16x8 af = *(const f16x8*)&A[arow + ks * 32 + kq];
#pragma unroll
    for (int ct = 0; ct < 8; ++ct) {
      f16x8 bf = *(const f16x8*)&Ws[(ct * 16 + cl) * 136 + ks * 32 + kq];
      acc[ct] = __builtin_amdgcn_mfma_f32_16x16x32_f16(af, bf, acc[ct], 0, 0, 0);
    }
  }
}
__device__ inline void mfma_regA(f32x4* acc, const f16x8* af, const ushort* Ws,
                                 int lane) {
  int cl = lane & 15, kq = (lane >> 4) * 8;
#pragma unroll
  for (int ks = 0; ks < 4; ++ks) {
#pragma unroll
    for (int ct = 0; ct < 8; ++ct) {
      f16x8 bf = *(const f16x8*)&Ws[(ct * 16 + cl) * 136 + ks * 32 + kq];
      acc[ct] = __builtin_amdgcn_mfma_f32_16x16x32_f16(af[ks], bf, acc[ct], 0, 0, 0);
    }
  }
}

// ---------------------------------------------------------------------------
__global__ __launch_bounds__(256) void count_int_kernel(const int* __restrict__ dst,
                                                        int* __restrict__ cnti, int E) {
  int e = blockIdx.x * 256 + threadIdx.x;
  if (e < E) atomicAdd(&cnti[dst[e]], 1);
}
__global__ __launch_bounds__(256) void scan_block_sum(const int* __restrict__ cnti,
                                                      int* __restrict__ bsum, int N) {
  int i = blockIdx.x * 256 + threadIdx.x;
  int v = (i < N) ? cnti[i] : 0;
#pragma unroll
  for (int o = 1; o < 64; o <<= 1) v += __shfl_xor(v, o);
  __shared__ int wsum[4];
  if ((threadIdx.x & 63) == 0) wsum[threadIdx.x >> 6] = v;
  __syncthreads();
  if (threadIdx.x == 0) bsum[blockIdx.x] = wsum[0] + wsum[1] + wsum[2] + wsum[3];
}
__global__ __launch_bounds__(256) void scan_partials(int* __restrict__ bsum, int nb) {
  __shared__ int s[256];
  int t = threadIdx.x;
  int v = (t < nb) ? bsum[t] : 0;
  s[t] = v;
  __syncthreads();
  for (int o = 1; o < 256; o <<= 1) {
    int u = (t >= o) ? s[t - o] : 0;
    __syncthreads();
    s[t] += u;
    __syncthreads();
  }
  if (t < nb) bsum[t] = s[t] - v;
}
__global__ __launch_bounds__(256) void scan_final(const int* __restrict__ cnti,
                                                  const int* __restrict__ bsum,
                                                  int* __restrict__ rowptr,
                                                  float* __restrict__ invf, int N) {
  __shared__ int s[256];
  int i = blockIdx.x * 256 + threadIdx.x;
  int t = threadIdx.x;
  int v = (i < N) ? cnti[i] : 0;
  s[t] = v;
  __syncthreads();
  for (int o = 1; o < 256; o <<= 1) {
    int u = (t >= o) ? s[t - o] : 0;
    __syncthreads();
    s[t] += u;
    __syncthreads();
  }
  if (i < N) {
    rowptr[i] = bsum[blockIdx.x] + s[t] - v;
    invf[i] = 1.f / (float)max(v, 1);
  }
}
__global__ __launch_bounds__(256) void scatter_kernel(
    const int* __restrict__ src, const int* __restrict__ dst,
    const float4* __restrict__ ea, const int* __restrict__ rowptr,
    int* __restrict__ tmpc, int* __restrict__ srcs, int* __restrict__ dsts,
    float4* __restrict__ eas, int E) {
  int e = blockIdx.x * 256 + threadIdx.x;
  if (e >= E) return;
  int d = dst[e];
  int r = atomicAdd(&tmpc[d], 1);
  int p = rowptr[d] + r;
  srcs[p] = src[e];
  dsts[p] = d;
  eas[p] = ea[e];
}

// ---------------------------------------------------------------------------
struct WPtrs { const float* src[22]; };
__global__ __launch_bounds__(256) void wconv_kernel(WPtrs p, ushort* __restrict__ wtb,
                                                    ushort* __restrict__ wlin) {
  int m = blockIdx.y;
  int idx = blockIdx.x * 256 + threadIdx.x;
  if (m == 21) {
    if (idx >= 4096) return;
    int n = idx >> 5, k = idx & 31;
    wlin[idx] = (k < 16) ? f2h(p.src[21][k * 128 + n]) : (ushort)0;
  } else {
    int n = idx >> 7, k = idx & 127;
    wtb[(size_t)m * 16384 + idx] = f2h(p.src[m][k * 128 + n]);
  }
}

// ---------------------------------------------------------------------------
__global__ __launch_bounds__(256) void lin_hw_kernel(
    const float* __restrict__ x, const ushort* __restrict__ wlin,
    const float* __restrict__ lb, const ushort* __restrict__ mw1t,
    const float* __restrict__ mb1, float* __restrict__ h,
    ushort* __restrict__ hwb, int N) {
  __shared__ char smem[69632] __attribute__((aligned(16)));
  ushort* xb  = (ushort*)smem;
  ushort* wsl = (ushort*)(smem + 4096);
  ushort* As1 = (ushort*)(smem + 12288);
  ushort* Ws  = (ushort*)(smem + 34816);
  int t = threadIdx.x, lane = t & 63, wave = t >> 6;
  int m0 = blockIdx.x * 64;
  int cl = lane & 15, kq = (lane >> 4) * 8;

  for (int i = t; i < 2048; i += 256) {
    int row = i >> 5, c = i & 31;
    int m = m0 + row;
    xb[i] = (c < 16 && m < N) ? f2h(x[(size_t)m * 16 + c]) : (ushort)0;
  }
  for (int i = t; i < 4096 / 8; i += 256)
    *(uint4*)&wsl[i * 8] = *(const uint4*)&wlin[i * 8];
  stage_w<256>(Ws, mw1t, t);
  __syncthreads();

  f32x4 acc[8];
#pragma unroll
  for (int i = 0; i < 8; ++i)
#pragma unroll
    for (int j = 0; j < 4; ++j) acc[i][j] = 0.f;
  {
    f16x8 af = *(const f16x8*)&xb[(wave * 16 + cl) * 32 + kq];
#pragma unroll
    for (int ct = 0; ct < 8; ++ct) {
      f16x8 bf = *(const f16x8*)&wsl[(ct * 16 + cl) * 32 + kq];
      acc[ct] = __builtin_amdgcn_mfma_f32_16x16x32_f16(af, bf, acc[ct], 0, 0, 0);
    }
  }
#pragma unroll
  for (int reg = 0; reg < 4; ++reg) {
    int row = wave * 16 + (lane >> 4) * 4 + reg;
    int m = m0 + row;
#pragma unroll
    for (int ct = 0; ct < 8; ++ct) {
      int col = ct * 16 + cl;
      float v = fmaxf(acc[ct][reg] + lb[col], 0.f);
      if (m < N) h[(size_t)m * 128 + col] = v;
      As1[row * 136 + col] = f2h(v);
    }
  }
  __syncthreads();
  f32x4 acc2[8];
#pragma unroll
  for (int i = 0; i < 8; ++i)
#pragma unroll
    for (int j = 0; j < 4; ++j) acc2[i][j] = 0.f;
  mfma_4ks(acc2, As1, Ws, wave, lane);
#pragma unroll
  for (int reg = 0; reg < 4; ++reg) {
    int m = m0 + wave * 16 + (lane >> 4) * 4 + reg;
    if (m >= N) continue;
#pragma unroll
    for (int ct = 0; ct < 8; ++ct) {
      int col = ct * 16 + cl;
      hwb[(size_t)m * 128 + col] = f2h(acc2[ct][reg] + mb1[col]);
    }
  }
}

// ---------------------------------------------------------------------------
// edge kernel v9 (R13 winner): 256 threads, 128 sorted edges/tile; f16 packed
// m1-build; A-frags in regs; in-register segmented reduction.
__global__ __launch_bounds__(256, 4) void edge_kernel_v9(
    const ushort* __restrict__ hw, const float4* __restrict__ eas,
    const int* __restrict__ srcs, const int* __restrict__ dsts,
    const ushort* __restrict__ W2t, const float* __restrict__ Wea,
    const float* __restrict__ b2, float* __restrict__ agg, int E) {
  __shared__ ushort Ws[128 * 136];
  __shared__ uint weaH[64][4];
  __shared__ float b2s[128];
  __shared__ int dss[130];
  int t = threadIdx.x, lane = t & 63, wave = t >> 6;
  int cl = lane & 15, g = lane >> 4;
  int p0 = blockIdx.x * 128;
  int base = wave * 32;

  int e0 = p0 + base + cl, e1 = e0 + 16;
  bool v0 = e0 < E, v1 = e1 < E;
  int s0 = v0 ? srcs[e0] : 0, s1 = v1 ? srcs[e1] : 0;
  float4 ea0 = v0 ? eas[e0] : make_float4(0.f, 0.f, 0.f, 0.f);
  float4 ea1 = v1 ? eas[e1] : make_float4(0.f, 0.f, 0.f, 0.f);
  uint4 hv0[4], hv1[4];
  {
    const ushort* h0 = hw + (size_t)s0 * 128 + g * 8;
    const ushort* h1 = hw + (size_t)s1 * 128 + g * 8;
#pragma unroll
    for (int ks = 0; ks < 4; ++ks) {
      hv0[ks] = v0 ? *(const uint4*)&h0[ks * 32] : make_uint4(0, 0, 0, 0);
      hv1[ks] = v1 ? *(const uint4*)&h1[ks * 32] : make_uint4(0, 0, 0, 0);
    }
  }

  stage_w<256>(Ws, W2t, t);
  if (t < 64) {
    weaH[t][0] = pk2(Wea[2 * t], Wea[2 * t + 1]);
    weaH[t][1] = pk2(Wea[128 + 2 * t], Wea[128 + 2 * t + 1]);
    weaH[t][2] = pk2(Wea[256 + 2 * t], Wea[256 + 2 * t + 1]);
    weaH[t][3] = pk2(Wea[384 + 2 * t], Wea[384 + 2 * t + 1]);
  }
  if (t < 128) {
    b2s[t] = b2[t];
    dss[1 + t] = (p0 + t < E) ? dsts[p0 + t] : -1;
  }
  if (t == 0) dss[0] = (p0 > 0) ? dsts[p0 - 1] : -2;
  if (t == 1) dss[129] = (p0 + 128 < E) ? dsts[p0 + 128] : -3;
  __syncthreads();

  uint e0b[4] = {pk2(ea0.x, ea0.x), pk2(ea0.y, ea0.y), pk2(ea0.z, ea0.z), pk2(ea0.w, ea0.w)};
  uint e1b[4] = {pk2(ea1.x, ea1.x), pk2(ea1.y, ea1.y), pk2(ea1.z, ea1.z), pk2(ea1.w, ea1.w)};

  f16x8 af0[4], af1[4];
  f16x2 z2 = {};
#pragma unroll
  for (int ks = 0; ks < 4; ++ks) {
    union { uint u32[4]; f16x8 v; } o0, o1;
    const uint* q0 = (const uint*)&hv0[ks];
    const uint* q1 = (const uint*)&hv1[ks];
    int k2b = ks * 16 + g * 4;
#pragma unroll
    for (int p = 0; p < 4; ++p) {
      uint4 w4 = *(const uint4*)&weaH[k2b + p][0];
      f16x2 m0h = bch(q0[p]);
      f16x2 m1h = bch(q1[p]);
      m0h += bch(e0b[0]) * bch(w4.x); m1h += bch(e1b[0]) * bch(w4.x);
      m0h += bch(e0b[1]) * bch(w4.y); m1h += bch(e1b[1]) * bch(w4.y);
      m0h += bch(e0b[2]) * bch(w4.z); m1h += bch(e1b[2]) * bch(w4.z);
      m0h += bch(e0b[3]) * bch(w4.w); m1h += bch(e1b[3]) * bch(w4.w);
      o0.u32[p] = __builtin_bit_cast(uint, __builtin_elementwise_max(m0h, z2));
      o1.u32[p] = __builtin_bit_cast(uint, __builtin_elementwise_max(m1h, z2));
    }
    af0[ks] = o0.v; af1[ks] = o1.v;
  }

  f32x4 acc0[8], acc1[8];
#pragma unroll
  for (int i = 0; i < 8; ++i)
#pragma unroll
    for (int j = 0; j < 4; ++j) { acc0[i][j] = 0.f; acc1[i][j] = 0.f; }
#pragma unroll
  for (int ks = 0; ks < 4; ++ks) {
#pragma unroll
    for (int ct = 0; ct < 8; ++ct) {
      f16x8 bf = *(const f16x8*)&Ws[(ct * 16 + cl) * 136 + ks * 32 + g * 8];
      acc0[ct] = __builtin_amdgcn_mfma_f32_16x16x32_f16(af0[ks], bf, acc0[ct], 0, 0, 0);
      acc1[ct] = __builtin_amdgcn_mfma_f32_16x16x32_f16(af1[ks], bf, acc1[ct], 0, 0, 0);
    }
  }

#pragma unroll
  for (int ct = 0; ct < 8; ++ct) {
    float bb = b2s[ct * 16 + cl];
#pragma unroll
    for (int reg = 0; reg < 4; ++reg) {
      acc0[ct][reg] = fmaxf(acc0[ct][reg] + bb, 0.f);
      acc1[ct][reg] = fmaxf(acc1[ct][reg] + bb, 0.f);
    }
  }

  int rloc = lane & 31;
  int dmy = dss[1 + base + rloc];
  int dpv = dss[base + rloc];
  int dafter = dss[1 + base + 32];
  unsigned long long bm = __ballot(dmy != dpv);
  unsigned mask32 = (unsigned)bm | 1u;
  bool firstClosed = ((unsigned)bm & 1u) != 0;
  while (mask32) {
    int rOff = __ffs(mask32) - 1;
    unsigned rest = mask32 & (mask32 - 1);
    int eOff = rest ? (__ffs(rest) - 1) : 32;
    mask32 = rest;
    int d = __shfl(dmy, rOff);
    if (d < 0) continue;
    bool openL = (rOff == 0) && !firstClosed;
    bool openR = (eOff == 32) && (dafter == d);
    float ps[8];
#pragma unroll
    for (int ct = 0; ct < 8; ++ct) ps[ct] = 0.f;
#pragma unroll
    for (int reg = 0; reg < 4; ++reg) {
      int r0w = g * 4 + reg;
      bool in0 = (r0w >= rOff) && (r0w < eOff);
      bool in1 = (r0w + 16 >= rOff) && (r0w + 16 < eOff);
#pragma unroll
      for (int ct = 0; ct < 8; ++ct) {
        if (in0) ps[ct] += acc0[ct][reg];
        if (in1) ps[ct] += acc1[ct][reg];
      }
    }
#pragma unroll
    for (int ct = 0; ct < 8; ++ct) {
      ps[ct] += __shfl_xor(ps[ct], 16);
      ps[ct] += __shfl_xor(ps[ct], 32);
    }
    if (g == 0) {
      float* ag = &agg[(size_t)d * 128 + cl];
      if (openL || openR) {
#pragma unroll
        for (int ct = 0; ct < 8; ++ct) atomicAdd(&ag[ct * 16], ps[ct]);
      } else {
#pragma unroll
        for (int ct = 0; ct < 8; ++ct) ag[ct * 16] = ps[ct];
      }
    }
  }
}

// ---------------------------------------------------------------------------
// fused node phase (R13): 512 thr / 128 rows
__global__ __launch_bounds__(512, 2) void fused_update(
    const float* __restrict__ h, const float* __restrict__ agg,
    const float* __restrict__ inv, const ushort* __restrict__ Wu1a,
    const ushort* __restrict__ Wu1b, const ushort* __restrict__ Wu2,
    const float* __restrict__ b1, const float* __restrict__ b2,
    const ushort* __restrict__ Wn, const float* __restrict__ bn,
    float* __restrict__ h_out, ushort* __restrict__ hwb,
    const float* __restrict__ hw2, const float* __restrict__ hb2,
    float* __restrict__ out, int N, int is_last) {
  __shared__ char smem[69632] __attribute__((aligned(16)));
  ushort* As1 = (ushort*)smem;
  ushort* Ws  = (ushort*)(smem + 34816);
  float* otile = (float*)smem;
  float* w2s   = (float*)(smem + 66560);
  int t = threadIdx.x, lane = t & 63, wave = t >> 6;
  int m0 = blockIdx.x * 128;
  int cl = lane & 15, g = lane >> 4;

  int m2r = m0 + wave * 16 + cl;
  bool mv = m2r < N;
  float sI = mv ? inv[m2r] : 0.f;
  float4 ga[8];
  {
    const float* gp = agg + (size_t)(mv ? m2r : 0) * 128 + g * 8;
#pragma unroll
    for (int ks = 0; ks < 4; ++ks) {
      ga[ks * 2 + 0] = *(const float4*)&gp[ks * 32];
      ga[ks * 2 + 1] = *(const float4*)&gp[ks * 32 + 4];
    }
  }

  {
    int row = t >> 2, q = t & 3;
    int m = m0 + row;
    union { uint u32[16]; uint4 u4[4]; } a;
    if (m < N) {
      const float* hp = h + (size_t)m * 128 + q * 32;
#pragma unroll
      for (int j = 0; j < 8; ++j) {
        float4 hv = *(const float4*)&hp[j * 4];
        a.u32[j * 2 + 0] = pk2(hv.x, hv.y);
        a.u32[j * 2 + 1] = pk2(hv.z, hv.w);
      }
    } else {
#pragma unroll
      for (int j = 0; j < 16; ++j) a.u32[j] = 0;
    }
#pragma unroll
    for (int j = 0; j < 4; ++j)
      *(uint4*)&As1[row * 136 + q * 32 + j * 8] = a.u4[j];
  }
  stage_w<512>(Ws, Wu1a, t);
  __syncthreads();

  f32x4 acc[8];
#pragma unroll
  for (int i = 0; i < 8; ++i)
#pragma unroll
    for (int j = 0; j < 4; ++j) acc[i][j] = 0.f;
  mfma_4ks(acc, As1, Ws, wave, lane);
  __syncthreads();
  stage_w<512>(Ws, Wu1b, t);
  f16x8 af2[4];
#pragma unroll
  for (int ks = 0; ks < 4; ++ks) {
    union { uint u32[4]; f16x8 v; } o;
    const float* f = (const float*)&ga[ks * 2];
#pragma unroll
    for (int j = 0; j < 4; ++j)
      o.u32[j] = pk2(f[j * 2] * sI, f[j * 2 + 1] * sI);
    af2[ks] = o.v;
  }
  __syncthreads();
  mfma_regA(acc, af2, Ws, lane);
  __syncthreads();

#pragma unroll
  for (int reg = 0; reg < 4; ++reg) {
    int row = wave * 16 + g * 4 + reg;
#pragma unroll
    for (int ct = 0; ct < 8; ++ct) {
      int col = ct * 16 + cl;
      As1[row * 136 + col] = f2h(fmaxf(acc[ct][reg] + b1[col], 0.f));
    }
  }
  stage_w<512>(Ws, Wu2, t);
  __syncthreads();

  f32x4 acc2[8];
#pragma unroll
  for (int i = 0; i < 8; ++i)
#pragma unroll
    for (int j = 0; j < 4; ++j) acc2[i][j] = 0.f;
  mfma_4ks(acc2, As1, Ws, wave, lane);
  __syncthreads();

#pragma unroll
  for (int reg = 0; reg < 4; ++reg) {
    int row = wave * 16 + g * 4 + reg;
    int m = m0 + row;
#pragma unroll
    for (int ct = 0; ct < 8; ++ct) {
      int col = ct * 16 + cl;
      float v = acc2[ct][reg] + b2[col];
      if (m < N) v += h[(size_t)m * 128 + col];
      v = fmaxf(v, 0.f);
      if (!is_last && m < N) h_out[(size_t)m * 128 + col] = v;
      As1[row * 136 + col] = f2h(v);
    }
  }
  stage_w<512>(Ws, Wn, t);
  __syncthreads();

  f32x4 acc3[8];
#pragma unroll
  for (int i = 0; i < 8; ++i)
#pragma unroll
    for (int j = 0; j < 4; ++j) acc3[i][j] = 0.f;
  mfma_4ks(acc3, As1, Ws, wave, lane);

  if (!is_last) {
#pragma unroll
    for (int reg = 0; reg < 4; ++reg) {
      int m = m0 + wave * 16 + g * 4 + reg;
      if (m >= N) continue;
#pragma unroll
      for (int ct = 0; ct < 8; ++ct) {
        int col = ct * 16 + cl;
        hwb[(size_t)m * 128 + col] = f2h(acc3[ct][reg] + bn[col]);
      }
    }
  } else {
    __syncthreads();
#pragma unroll
    for (int reg = 0; reg < 4; ++reg) {
      int row = wave * 16 + g * 4 + reg;
#pragma unroll
      for (int ct = 0; ct < 8; ++ct) {
        int col = ct * 16 + cl;
        otile[row * 130 + col] = fmaxf(acc3[ct][reg] + bn[col], 0.f);
      }
    }
    for (int i = t; i < 384; i += 512) w2s[i] = hw2[i];
    __syncthreads();
    if (t < 384) {
      int row = t / 3, c = t % 3;
      int m = m0 + row;
      if (m < N) {
        float s = hb2[c];
#pragma unroll 16
        for (int k = 0; k < 128; ++k) s += otile[row * 130 + k] * w2s[k * 3 + c];
        out[(size_t)m * 3 + c] = fmaxf(s, 0.f);
      }
    }
  }
}

// ---------------------------------------------------------------------------
extern "C" void kernel_launch(void* const* d_in, const int* in_sizes, int n_in,
                              void* d_out, int out_size, void* d_ws, size_t ws_size,
                              hipStream_t stream) {
  const float* x       = (const float*)d_in[0];
  const int*   ei      = (const int*)  d_in[1];
  const float* ea      = (const float*)d_in[2];
  const float* lin_w   = (const float*)d_in[3];
  const float* lin_b   = (const float*)d_in[4];
  const float* msg_w1  = (const float*)d_in[5];
  const float* msg_b1  = (const float*)d_in[6];
  const float* msg_w2  = (const float*)d_in[7];
  const float* msg_b2  = (const float*)d_in[8];
  const float* upd_w1  = (const float*)d_in[9];
  const float* upd_b1  = (const float*)d_in[10];
  const float* upd_w2  = (const float*)d_in[11];
  const float* upd_b2  = (const float*)d_in[12];
  const float* head_w1 = (const float*)d_in[13];
  const float* head_b1 = (const float*)d_in[14];
  const float* head_w2 = (const float*)d_in[15];
  const float* head_b2 = (const float*)d_in[16];

  int N = in_sizes[0] / 16;
  int E = in_sizes[1] / 2;
  const int* src = ei;
  const int* dst = ei + E;

  float* ws = (float*)d_ws;
  size_t NH = (size_t)N * 128;
  size_t Nr = ((size_t)N + 4) & ~(size_t)3;
  size_t Er = ((size_t)E + 3) & ~(size_t)3;
  size_t off = 0;
  float*  h    = ws + off; off += NH;
  float*  agg  = ws + off; off += NH;
  float4* eas  = (float4*)(ws + off); off += 4 * Er;
  float*  invf = ws + off; off += Nr;
  ushort* wtb  = (ushort*)(ws + off); off += (size_t)21 * 16384 / 2;
  ushort* wlin = (ushort*)(ws + off); off += 4096 / 2;
  ushort* hwb  = (ushort*)(ws + off); off += NH / 2;
  int*    cnti = (int*)(ws + off); off += Nr;
  int*    tmpc = (int*)(ws + off); off += Nr;
  int*    rowp = (int*)(ws + off); off += Nr;
  int*    srcs = (int*)(ws + off); off += Er;
  int*    dsts = (int*)(ws + off); off += Er;
  int*    bsum = (int*)(ws + off); off += 256;
  float*  out  = (float*)d_out;

  WPtrs wp;
  for (int l = 0; l < 4; ++l) {
    wp.src[l * 5 + 0] = msg_w1 + (size_t)l * 132 * 128;
    wp.src[l * 5 + 1] = msg_w2 + (size_t)l * 128 * 128;
    wp.src[l * 5 + 2] = upd_w1 + (size_t)l * 256 * 128;
    wp.src[l * 5 + 3] = upd_w1 + (size_t)l * 256 * 128 + 128 * 128;
    wp.src[l * 5 + 4] = upd_w2 + (size_t)l * 128 * 128;
  }
  wp.src[20] = head_w1;
  wp.src[21] = lin_w;

  int ngrid = (N + 63) / 64;
  int fgrid = (N + 127) / 128;
  int egrid = (E + 127) / 128;
  int nscan = (N + 255) / 256;

  hipMemsetAsync(cnti, 0, Nr * 4, stream);
  hipMemsetAsync(tmpc, 0, Nr * 4, stream);
  wconv_kernel<<<dim3(64, 22), 256, 0, stream>>>(wp, wtb, wlin);
  count_int_kernel<<<(E + 255) / 256, 256, 0, stream>>>(dst, cnti, E);
  scan_block_sum<<<nscan, 256, 0, stream>>>(cnti, bsum, N);
  scan_partials<<<1, 256, 0, stream>>>(bsum, nscan);
  scan_final<<<nscan, 256, 0, stream>>>(cnti, bsum, rowp, invf, N);
  scatter_kernel<<<(E + 255) / 256, 256, 0, stream>>>(src, dst, (const float4*)ea,
                                                      rowp, tmpc, srcs, dsts, eas, E);
  lin_hw_kernel<<<ngrid, 256, 0, stream>>>(x, wlin, lin_b, wtb, msg_b1, h, hwb, N);

  for (int l = 0; l < 4; ++l) {
    const ushort* mw2t  = wtb + (size_t)(l * 5 + 1) * 16384;
    const ushort* wu1at = wtb + (size_t)(l * 5 + 2) * 16384;
    const ushort* wu1bt = wtb + (size_t)(l * 5 + 3) * 16384;
    const ushort* wu2t  = wtb + (size_t)(l * 5 + 4) * 16384;
    const float*  wea   = msg_w1 + (size_t)l * 132 * 128 + 128 * 128;
    int last = (l == 3);
    const ushort* Wn = last ? (wtb + (size_t)20 * 16384)
                            : (wtb + (size_t)((l + 1) * 5 + 0) * 16384);
    const float* bn = last ? head_b1 : (msg_b1 + (l + 1) * 128);

    hipMemsetAsync(agg, 0, NH * sizeof(float), stream);
    edge_kernel_v9<<<egrid, 256, 0, stream>>>(hwb, eas, srcs, dsts, mw2t, wea,
                                              msg_b2 + l * 128, agg, E);
    fused_update<<<fgrid, 512, 0, stream>>>(h, agg, invf, wu1at, wu1bt, wu2t,
                                            upd_b1 + l * 128, upd_b2 + l * 128,
                                            Wn, bn, h, last ? nullptr : hwb,
                                            head_w2, head_b2, out, N, last);
  }
}